// Round 4
// baseline (272.332 us; speedup 1.0000x reference)
//
#include <hip/hip_runtime.h>

// BERT joint NER+relation head on MI355X (gfx950).
// Inputs: fp32 (reference dtypes). Output: fp32 flat [tags(1024) | scores(3145728)].
// Pipeline: prep (V frags, ner, lab2) -> fused GEMM+Viterbi -> scorer (MFMA).

typedef unsigned short ushort_t;
typedef __attribute__((ext_vector_type(8))) short bf16x8;
typedef __attribute__((ext_vector_type(4))) float f32x4;
typedef __attribute__((ext_vector_type(4))) int i32x4;

#define C2F 2.8853900817779268f  // 2*log2(e)

// workspace offsets (bytes), all 16-aligned; total 3,400,960 B
#define WS_UW2   0u         // ushort [1024][1600] : bf16( 2log2e*(embed@[U|W] + bias) )
#define WS_NER   3276800u   // float  [1024][9]
#define WS_VFRAG 3313664u   // ushort [25][64][8]  : V as 16x16x32 B-fragments (bf16)
#define WS_LAB2  3339264u   // float  [9][1600]    : 2log2e*(label_emb@[U|W][768:])
#define WS_TAGS  3396864u   // int    [1024]

__device__ __forceinline__ unsigned f2b(float f){
  unsigned u = __float_as_uint(f);
  return (u + 0x7FFFu + ((u>>16)&1u)) >> 16;   // RNE, finite inputs only
}
__device__ __forceinline__ float lo16(int v){ return __uint_as_float(((unsigned)v)<<16); }
__device__ __forceinline__ float hi16(int v){ return __uint_as_float(((unsigned)v)&0xFFFF0000u); }
__device__ __forceinline__ float tanh_fast(float x2){  // x2 = 2*log2e*x -> tanh(x)
  float e = __builtin_amdgcn_exp2f(x2);
  float r = __builtin_amdgcn_rcpf(e + 1.0f);
  return __builtin_fmaf(-2.0f, r, 1.0f);
}

// ---------------------------------------------------------------- prep ----
// blocks [0,50): V frags; [50,306): ner rows; [306,363): lab2
__global__ __launch_bounds__(256) void prep_kernel(
    const float* __restrict__ embed, const float* __restrict__ lw,
    const float* __restrict__ lb,    const float* __restrict__ lemb,
    const float* __restrict__ uw,    const float* __restrict__ ww,
    const float* __restrict__ vw,    char* __restrict__ ws)
{
  int bx = blockIdx.x, t = threadIdx.x;
  if (bx < 50) {                         // V B-fragments: B[k=quad*8+jj][n=lane&15]
    ushort_t* vf = (ushort_t*)(ws + WS_VFRAG);
    int idx = bx*256 + t;                // < 12800
    int jj = idx & 7, lane = (idx>>3) & 63, c = idx >> 9;
    int h = c*32 + ((lane>>4)<<3) + jj;
    int n = lane & 15;
    vf[idx] = (h < 798 && n < 12) ? (ushort_t)f2b(vw[h*12 + n]) : (ushort_t)0;
  } else if (bx < 306) {                 // ner = embed@linear_w + b (one wave per row, fp32)
    float* ner = (float*)(ws + WS_NER);
    int w = t >> 6, lane = t & 63;
    int row = (bx-50)*4 + w;             // < 1024
    float acc[9];
    #pragma unroll
    for (int i=0;i<9;i++) acc[i]=0.f;
    const float* erow = embed + row*768;
    for (int kk=0; kk<12; kk++) {
      int k = kk*64 + lane;
      float e = erow[k];
      #pragma unroll
      for (int i=0;i<9;i++) acc[i] = __builtin_fmaf(e, lw[k*9+i], acc[i]);
    }
    #pragma unroll
    for (int i=0;i<9;i++) {
      float v = acc[i];
      for (int off=32; off>0; off>>=1) v += __shfl_down(v, off);
      if (lane == 0) ner[row*9+i] = v + lb[i];
    }
  } else {                               // lab2[g][n] = C2 * (label_emb[g] @ [U|W][768:798, n])
    float* lab2 = (float*)(ws + WS_LAB2);
    int idx = (bx-306)*256 + t;
    if (idx < 14400) {
      int g = idx / 1600, n = idx - g*1600;
      const float* X = (n < 800) ? uw : ww;
      int nn = (n < 800) ? n : (n - 800);
      float v = 0.f;
      if (nn < 798) {
        float s = 0.f;
        for (int l=0;l<30;l++)
          s = __builtin_fmaf(lemb[g*30+l], X[(768+l)*798 + nn], s);
        v = s * C2F;
      }
      lab2[idx] = v;
    }
  }
}

// ------------------------------------------- fused GEMM (blocks 0..399) + Viterbi (block 400)
__global__ __launch_bounds__(256) void gemm_viterbi_kernel(
    const float* __restrict__ embed,
    const float* __restrict__ uw,    const float* __restrict__ ub,
    const float* __restrict__ ww,    const float* __restrict__ wb,
    const float* __restrict__ start_t, const float* __restrict__ trans,
    const float* __restrict__ end_t,
    char* __restrict__ ws, float* __restrict__ out_tags)
{
  __shared__ char smem[65472];           // union: GEMM tiles (10.2KB) / Viterbi em+hist (63.9KB)
  int bx = blockIdx.x, tid = threadIdx.x;
  if (bx < 400) {
    // uw2[1024][1600] = bf16( C2 * (embed[1024,768] @ [U_w|W_w][768,1600] + bias) )
    ushort_t (*As)[40] = (ushort_t(*)[40])smem;           // 64 rows x 32 k, +8 pad
    ushort_t (*Bs)[40] = (ushort_t(*)[40])(smem + 5120);  // Bs[n_local][k_local]
    ushort_t* uw2 = (ushort_t*)(ws + WS_UW2);
    int bm = bx & 15, bn = bx >> 4;
    int M0 = bm*64, N0 = bn*64;
    int w = tid>>6, lane = tid&63;
    int wr = w>>1, wc = w&1;
    int m16 = lane&15, quad = lane>>4;
    int nl = tid>>2, k8 = (tid&3)<<3;
    // B source for this thread's column (on-the-fly transpose from U_w/W_w fp32)
    int nn = N0 + nl;
    const float* bsrc = uw; int bcol = 0; bool bzero = true;
    if (nn < 798)       { bsrc = uw; bcol = nn;     bzero = false; }
    else if (nn >= 800 && nn < 1598) { bsrc = ww; bcol = nn-800; bzero = false; }
    f32x4 acc[2][2];
    #pragma unroll
    for (int mi=0;mi<2;mi++)
      #pragma unroll
      for (int ni=0;ni<2;ni++) acc[mi][ni] = (f32x4){0.f,0.f,0.f,0.f};
    for (int k0=0; k0<768; k0+=32) {
      // A: 8 fp32 -> 8 bf16 packed
      const float* ap = &embed[(M0+nl)*768 + k0 + k8];
      f32x4 a_lo = *(const f32x4*)ap;
      f32x4 a_hi = *(const f32x4*)(ap+4);
      unsigned pa[4];
      pa[0] = f2b(a_lo.x) | (f2b(a_lo.y)<<16);
      pa[1] = f2b(a_lo.z) | (f2b(a_lo.w)<<16);
      pa[2] = f2b(a_hi.x) | (f2b(a_hi.y)<<16);
      pa[3] = f2b(a_hi.z) | (f2b(a_hi.w)<<16);
      *(i32x4*)&As[nl][k8] = (i32x4){(int)pa[0],(int)pa[1],(int)pa[2],(int)pa[3]};
      // B: gather 8 fp32 down the column -> bf16 pack
      unsigned pk[4];
      #pragma unroll
      for (int qq=0; qq<4; qq++) {
        unsigned e0 = bzero ? 0u : f2b(bsrc[(k0+k8+2*qq  )*798 + bcol]);
        unsigned e1 = bzero ? 0u : f2b(bsrc[(k0+k8+2*qq+1)*798 + bcol]);
        pk[qq] = e0 | (e1<<16);
      }
      *(i32x4*)&Bs[nl][k8] = (i32x4){(int)pk[0],(int)pk[1],(int)pk[2],(int)pk[3]};
      __syncthreads();
      bf16x8 a0 = *(const bf16x8*)&As[wr*32      + m16][quad*8];
      bf16x8 a1 = *(const bf16x8*)&As[wr*32 + 16 + m16][quad*8];
      bf16x8 b0 = *(const bf16x8*)&Bs[wc*32      + m16][quad*8];
      bf16x8 b1 = *(const bf16x8*)&Bs[wc*32 + 16 + m16][quad*8];
      acc[0][0] = __builtin_amdgcn_mfma_f32_16x16x32_bf16(a0,b0,acc[0][0],0,0,0);
      acc[0][1] = __builtin_amdgcn_mfma_f32_16x16x32_bf16(a0,b1,acc[0][1],0,0,0);
      acc[1][0] = __builtin_amdgcn_mfma_f32_16x16x32_bf16(a1,b0,acc[1][0],0,0,0);
      acc[1][1] = __builtin_amdgcn_mfma_f32_16x16x32_bf16(a1,b1,acc[1][1],0,0,0);
      __syncthreads();
    }
    #pragma unroll
    for (int mi=0;mi<2;mi++)
      #pragma unroll
      for (int ni=0;ni<2;ni++)
        #pragma unroll
        for (int reg=0;reg<4;reg++) {
          int gm = M0 + wr*32 + mi*16 + quad*4 + reg;
          int gn = N0 + wc*32 + ni*16 + m16;
          float bias = 0.f;
          if (gn < 798) bias = ub[gn];
          else if (gn >= 800 && gn < 1598) bias = wb[gn-800];
          float v = (acc[mi][ni][reg] + bias) * C2F;
          uw2[gm*1600 + gn] = (ushort_t)f2b(v);
        }
  } else {
    // Viterbi: 4 waves, one batch each; fp32; strict-> keeps first max like jnp.argmax
    float* em = (float*)smem;                             // [4][256][12]
    unsigned char* hist = (unsigned char*)(smem + 49152); // [4][255][16]
    const float* ner = (const float*)(ws + WS_NER);
    int* tags = (int*)(ws + WS_TAGS);
    for (int idx = tid; idx < 9216; idx += 256) {
      int bb = idx / 2304, rem = idx - bb*2304;
      int s = rem / 9, tt2 = rem - s*9;
      em[(bb*256+s)*12 + tt2] = ner[(bb*256+s)*9 + tt2];
    }
    __syncthreads();
    int w = tid>>6, lane = tid&63;
    int b = w;
    int tt = lane < 9 ? lane : 8;         // clamp: lanes>=9 compute junk, never read
    float tcol[9];
    #pragma unroll
    for (int p=0;p<9;p++) tcol[p] = trans[p*9+tt];
    float score = start_t[tt] + em[(b*256 + 0)*12 + tt];
    for (int s=1; s<256; s++) {
      float sp[9];
      #pragma unroll
      for (int p=0;p<9;p++) sp[p] = __shfl(score, p);
      float best = -3.0e38f; int arg = 0;
      #pragma unroll
      for (int p=0;p<9;p++) {
        float c = sp[p] + tcol[p];
        if (c > best) { best = c; arg = p; }
      }
      score = best + em[(b*256 + s)*12 + tt];
      if (lane < 9) hist[(b*255 + (s-1))*16 + lane] = (unsigned char)arg;
    }
    float fin = score + end_t[tt];
    float bv = -3.0e38f; int ba = 0;
    #pragma unroll
    for (int p=0;p<9;p++) {
      float v = __shfl(fin, p);
      if (v > bv) { bv = v; ba = p; }
    }
    if (lane == 0) {
      int cur = ba;
      tags[b*256 + 255] = cur;
      out_tags[b*256 + 255] = (float)cur;
      for (int k=254; k>=0; k--) {
        cur = hist[(b*255 + k)*16 + cur];
        tags[b*256 + k] = cur;
        out_tags[b*256 + k] = (float)cur;
      }
    }
  }
}

// --------------------------------------------------------------- scorer ----
// scores[b,i,j,r] = sum_h tanh(u[b,i,h]+w[b,j,h]) * V[h,r]; diag(none_idx)=100
__global__ __launch_bounds__(256) void scorer_kernel(
    char* __restrict__ ws, const int* __restrict__ none_p,
    float* __restrict__ d_out)
{
  __shared__ ushort_t su[16][808];   // stride 808: 2-way LDS aliasing only (free)
  __shared__ ushort_t sw[16][808];
  const ushort_t* uw2 = (const ushort_t*)(ws + WS_UW2);
  const float* lab2   = (const float*)(ws + WS_LAB2);
  const ushort_t* vf  = (const ushort_t*)(ws + WS_VFRAG);
  const int* tags     = (const int*)(ws + WS_TAGS);
  float* out_sc = d_out + 1024;
  int bx = blockIdx.x, tid = threadIdx.x;
  int b = bx >> 8, ti = (bx>>4)&15, tj = bx&15;
  int I0 = ti*16, J0 = tj*16, bS = b*256;

  for (int idx = tid; idx < 1600; idx += 256) {   // stage su = u2 + lab2[tag] (bf16)
    int row = idx / 100, c8 = idx - row*100, kc = c8*8;
    int grow = bS + I0 + row;
    int tag = tags[grow];
    i32x4 uv = *(const i32x4*)(uw2 + (size_t)grow*1600 + kc);
    const float* lp = lab2 + tag*1600 + kc;
    f32x4 l0 = *(const f32x4*)lp;
    f32x4 l1 = *(const f32x4*)(lp+4);
    unsigned q0 = f2b(lo16(uv.x)+l0.x) | (f2b(hi16(uv.x)+l0.y)<<16);
    unsigned q1 = f2b(lo16(uv.y)+l0.z) | (f2b(hi16(uv.y)+l0.w)<<16);
    unsigned q2 = f2b(lo16(uv.z)+l1.x) | (f2b(hi16(uv.z)+l1.y)<<16);
    unsigned q3 = f2b(lo16(uv.w)+l1.z) | (f2b(hi16(uv.w)+l1.w)<<16);
    *(i32x4*)&su[row][kc] = (i32x4){(int)q0,(int)q1,(int)q2,(int)q3};
  }
  for (int idx = tid; idx < 1600; idx += 256) {   // stage sw = w2 + lab2[tag] (bf16)
    int row = idx / 100, c8 = idx - row*100, kc = c8*8;
    int grow = bS + J0 + row;
    int tag = tags[grow];
    i32x4 uv = *(const i32x4*)(uw2 + (size_t)grow*1600 + 800 + kc);
    const float* lp = lab2 + tag*1600 + 800 + kc;
    f32x4 l0 = *(const f32x4*)lp;
    f32x4 l1 = *(const f32x4*)(lp+4);
    unsigned q0 = f2b(lo16(uv.x)+l0.x) | (f2b(hi16(uv.x)+l0.y)<<16);
    unsigned q1 = f2b(lo16(uv.y)+l0.z) | (f2b(hi16(uv.y)+l0.w)<<16);
    unsigned q2 = f2b(lo16(uv.z)+l1.x) | (f2b(hi16(uv.z)+l1.y)<<16);
    unsigned q3 = f2b(lo16(uv.w)+l1.z) | (f2b(hi16(uv.w)+l1.w)<<16);
    *(i32x4*)&sw[row][kc] = (i32x4){(int)q0,(int)q1,(int)q2,(int)q3};
  }
  __syncthreads();

  int lane = tid & 63, w = tid >> 6;
  int m16 = lane & 15, quad = lane >> 4;
  int none = *none_p;
  bf16x8 bf[25];                       // V B-frags, register-resident (~100 VGPR)
  #pragma unroll
  for (int c=0;c<25;c++) bf[c] = *(const bf16x8*)(vf + (c*64 + lane)*8);

  for (int it=0; it<4; it++) {
    int i = w*4 + it;                  // wave's i within the 16-row tile
    f32x4 acc = (f32x4){0.f,0.f,0.f,0.f};
    #pragma unroll
    for (int c=0;c<25;c++) {
      int koff = c*32 + quad*8;
      i32x4 uv = *(const i32x4*)&su[i][koff];     // broadcast within quad
      i32x4 wv = *(const i32x4*)&sw[m16][koff];   // lane's j row
      unsigned a0 = f2b(tanh_fast(lo16(uv.x)+lo16(wv.x))) | (f2b(tanh_fast(hi16(uv.x)+hi16(wv.x)))<<16);
      unsigned a1 = f2b(tanh_fast(lo16(uv.y)+lo16(wv.y))) | (f2b(tanh_fast(hi16(uv.y)+hi16(wv.y)))<<16);
      unsigned a2 = f2b(tanh_fast(lo16(uv.z)+lo16(wv.z))) | (f2b(tanh_fast(hi16(uv.z)+hi16(wv.z)))<<16);
      unsigned a3 = f2b(tanh_fast(lo16(uv.w)+lo16(wv.w))) | (f2b(tanh_fast(hi16(uv.w)+hi16(wv.w)))<<16);
      i32x4 avv = (i32x4){(int)a0,(int)a1,(int)a2,(int)a3};
      bf16x8 af = __builtin_bit_cast(bf16x8, avv);
      acc = __builtin_amdgcn_mfma_f32_16x16x32_bf16(af, bf[c], acc, 0,0,0);
    }
    int r = m16;                       // D: col=lane&15 -> r, row=quad*4+reg -> j_local
    if (r < 12) {
      int gi = I0 + i;
      #pragma unroll
      for (int reg=0; reg<4; reg++) {
        int gj = J0 + quad*4 + reg;
        float v = acc[reg];
        if (gi == gj && r == none) v = 100.0f;
        out_sc[(size_t)((bS + gi)*256 + gj)*12 + r] = v;
      }
    }
  }
}

extern "C" void kernel_launch(void* const* d_in, const int* in_sizes, int n_in,
                              void* d_out, int out_size, void* d_ws, size_t ws_size,
                              hipStream_t stream)
{
  const float* embed = (const float*)d_in[0];
  const float* lw    = (const float*)d_in[1];
  const float* lb    = (const float*)d_in[2];
  const float* st    = (const float*)d_in[3];
  const float* tr    = (const float*)d_in[4];
  const float* et    = (const float*)d_in[5];
  const float* lemb  = (const float*)d_in[6];
  const float* uw    = (const float*)d_in[7];
  const float* ub    = (const float*)d_in[8];
  const float* ww    = (const float*)d_in[9];
  const float* wb    = (const float*)d_in[10];
  const float* vw    = (const float*)d_in[11];
  const int* none_p  = (const int*)d_in[12];
  char* ws = (char*)d_ws;
  float* out = (float*)d_out;

  hipLaunchKernelGGL(prep_kernel, dim3(363), dim3(256), 0, stream,
                     embed, lw, lb, lemb, uw, ww, vw, ws);
  hipLaunchKernelGGL(gemm_viterbi_kernel, dim3(401), dim3(256), 0, stream,
                     embed, uw, ub, ww, wb, st, tr, et, ws, out);
  hipLaunchKernelGGL(scorer_kernel, dim3(1024), dim3(256), 0, stream,
                     ws, none_p, out);
}

// Round 5
// 251.731 us; speedup vs baseline: 1.0818x; 1.0818x over previous
//
#include <hip/hip_runtime.h>

// BERT joint NER+relation head on MI355X (gfx950).
// Inputs: fp32. Output: fp32 flat [tags(1024) | scores(3145728)].
// R5: v_perm trunc-pack for all fp32->bf16 pairs; coalesced+LDS-transposed B
// staging in GEMM; register prefetch across k-steps.

typedef unsigned short ushort_t;
typedef __attribute__((ext_vector_type(8))) short bf16x8;
typedef __attribute__((ext_vector_type(4))) float f32x4;
typedef __attribute__((ext_vector_type(4))) int i32x4;

#define C2F 2.8853900817779268f  // 2*log2(e)

// workspace offsets (bytes), all 16-aligned; total 3,400,960 B
#define WS_UW2   0u         // ushort [1024][1600] : bf16( 2log2e*(embed@[U|W] + bias) )
#define WS_NER   3276800u   // float  [1024][9]
#define WS_VFRAG 3313664u   // ushort [25][64][8]  : V as 16x16x32 B-fragments (bf16)
#define WS_LAB2  3339264u   // float  [9][1600]    : 2log2e*(label_emb@[U|W][768:])
#define WS_TAGS  3396864u   // int    [1024]

__device__ __forceinline__ unsigned f2b(float f){          // RNE, finite only
  unsigned u = __float_as_uint(f);
  return (u + 0x7FFFu + ((u>>16)&1u)) >> 16;
}
// bf16 pair via v_perm_b32 (truncation): bits[15:0]=bf16(lo), bits[31:16]=bf16(hi)
__device__ __forceinline__ unsigned pkbf16(float hi, float lo){
  return __builtin_amdgcn_perm(__float_as_uint(hi), __float_as_uint(lo), 0x07060302u);
}
__device__ __forceinline__ float lo16(int v){ return __uint_as_float(((unsigned)v)<<16); }
__device__ __forceinline__ float hi16(int v){ return __uint_as_float(((unsigned)v)&0xFFFF0000u); }
__device__ __forceinline__ float tanh_fast(float x2){  // x2 = 2*log2e*x -> tanh(x)
  float e = __builtin_amdgcn_exp2f(x2);
  float r = __builtin_amdgcn_rcpf(e + 1.0f);
  return __builtin_fmaf(-2.0f, r, 1.0f);
}

// ---------------------------------------------------------------- prep ----
// blocks [0,50): V frags; [50,306): ner rows; [306,363): lab2
__global__ __launch_bounds__(256) void prep_kernel(
    const float* __restrict__ embed, const float* __restrict__ lw,
    const float* __restrict__ lb,    const float* __restrict__ lemb,
    const float* __restrict__ uw,    const float* __restrict__ ww,
    const float* __restrict__ vw,    char* __restrict__ ws)
{
  int bx = blockIdx.x, t = threadIdx.x;
  if (bx < 50) {                         // V B-fragments: B[k=quad*8+jj][n=lane&15]
    ushort_t* vf = (ushort_t*)(ws + WS_VFRAG);
    int idx = bx*256 + t;                // < 12800
    int jj = idx & 7, lane = (idx>>3) & 63, c = idx >> 9;
    int h = c*32 + ((lane>>4)<<3) + jj;
    int n = lane & 15;
    vf[idx] = (h < 798 && n < 12) ? (ushort_t)f2b(vw[h*12 + n]) : (ushort_t)0;
  } else if (bx < 306) {                 // ner = embed@linear_w + b (one wave per row, fp32)
    float* ner = (float*)(ws + WS_NER);
    int w = t >> 6, lane = t & 63;
    int row = (bx-50)*4 + w;             // < 1024
    float acc[9];
    #pragma unroll
    for (int i=0;i<9;i++) acc[i]=0.f;
    const float* erow = embed + row*768;
    for (int kk=0; kk<12; kk++) {
      int k = kk*64 + lane;
      float e = erow[k];
      #pragma unroll
      for (int i=0;i<9;i++) acc[i] = __builtin_fmaf(e, lw[k*9+i], acc[i]);
    }
    #pragma unroll
    for (int i=0;i<9;i++) {
      float v = acc[i];
      for (int off=32; off>0; off>>=1) v += __shfl_down(v, off);
      if (lane == 0) ner[row*9+i] = v + lb[i];
    }
  } else {                               // lab2[g][n] = C2 * (label_emb[g] @ [U|W][768:798, n])
    float* lab2 = (float*)(ws + WS_LAB2);
    int idx = (bx-306)*256 + t;
    if (idx < 14400) {
      int g = idx / 1600, n = idx - g*1600;
      const float* X = (n < 800) ? uw : ww;
      int nn = (n < 800) ? n : (n - 800);
      float v = 0.f;
      if (nn < 798) {
        float s = 0.f;
        for (int l=0;l<30;l++)
          s = __builtin_fmaf(lemb[g*30+l], X[(768+l)*798 + nn], s);
        v = s * C2F;
      }
      lab2[idx] = v;
    }
  }
}

// ------------------------------------------- fused GEMM (blocks 0..399) + Viterbi (block 400)
__global__ __launch_bounds__(256) void gemm_viterbi_kernel(
    const float* __restrict__ embed,
    const float* __restrict__ uw,    const float* __restrict__ ub,
    const float* __restrict__ ww,    const float* __restrict__ wb,
    const float* __restrict__ start_t, const float* __restrict__ trans,
    const float* __restrict__ end_t,
    char* __restrict__ ws, float* __restrict__ out_tags)
{
  __shared__ char smem[65472];           // union: GEMM tiles (10.5KB) / Viterbi em+hist (63.9KB)
  int bx = blockIdx.x, tid = threadIdx.x;
  if (bx < 400) {
    // uw2[1024][1600] = bf16( C2 * (embed[1024,768] @ [U_w|W_w][768,1600] + bias) )
    ushort_t (*As)[40] = (ushort_t(*)[40])smem;            // [m][k] +8 pad, 5120 B
    ushort_t (*Bs)[42] = (ushort_t(*)[42])(smem + 5120);   // [n][k] +10 pad, 5376 B
    ushort_t* uw2 = (ushort_t*)(ws + WS_UW2);
    int bm = bx & 15, bn = bx >> 4;
    int M0 = bm*64, N0 = bn*64;
    int w = tid>>6, lane = tid&63;
    int wr = w>>1, wc = w&1;
    int m16 = lane&15, quad = lane>>4;
    // A staging coords: row nl, 8-k chunk k8
    int nl = tid>>2, k8 = (tid&3)<<3;
    // B staging coords: column n (coalesced lanes), k-pair per wave
    int bnn = tid & 63, bw = tid >> 6;
    int gn = N0 + bnn;
    const float* bsrc = uw; int bcol = 0; bool bzero = true;
    if (gn < 798)                    { bsrc = uw; bcol = gn;     bzero = false; }
    else if (gn >= 800 && gn < 1598) { bsrc = ww; bcol = gn-800; bzero = false; }

    f32x4 acc[2][2];
    #pragma unroll
    for (int mi=0;mi<2;mi++)
      #pragma unroll
      for (int ni=0;ni<2;ni++) acc[mi][ni] = (f32x4){0.f,0.f,0.f,0.f};

    // ---- register prefetch for k0=0
    f32x4 a_lo, a_hi; float bvals[8];
    {
      const float* ap = &embed[(M0+nl)*768 + k8];
      a_lo = *(const f32x4*)ap; a_hi = *(const f32x4*)(ap+4);
      #pragma unroll
      for (int r=0;r<4;r++) {
        int kk = r*8 + bw*2;
        bvals[2*r]   = bzero ? 0.f : bsrc[(kk  )*798 + bcol];
        bvals[2*r+1] = bzero ? 0.f : bsrc[(kk+1)*798 + bcol];
      }
    }
    for (int k0=0; k0<768; k0+=32) {
      // commit prefetched tile to LDS
      i32x4 av = (i32x4){ (int)pkbf16(a_lo.y,a_lo.x), (int)pkbf16(a_lo.w,a_lo.z),
                          (int)pkbf16(a_hi.y,a_hi.x), (int)pkbf16(a_hi.w,a_hi.z) };
      *(i32x4*)&As[nl][k8] = av;
      #pragma unroll
      for (int r=0;r<4;r++) {
        int kk = r*8 + bw*2;
        *(unsigned*)&Bs[bnn][kk] = pkbf16(bvals[2*r+1], bvals[2*r]);
      }
      __syncthreads();
      // prefetch next tile while MFMA phase runs
      if (k0 + 32 < 768) {
        const float* ap = &embed[(M0+nl)*768 + k0 + 32 + k8];
        a_lo = *(const f32x4*)ap; a_hi = *(const f32x4*)(ap+4);
        #pragma unroll
        for (int r=0;r<4;r++) {
          int kk = r*8 + bw*2;
          bvals[2*r]   = bzero ? 0.f : bsrc[(k0+32+kk  )*798 + bcol];
          bvals[2*r+1] = bzero ? 0.f : bsrc[(k0+32+kk+1)*798 + bcol];
        }
      }
      bf16x8 a0 = *(const bf16x8*)&As[wr*32      + m16][quad*8];
      bf16x8 a1 = *(const bf16x8*)&As[wr*32 + 16 + m16][quad*8];
      bf16x8 b0 = *(const bf16x8*)&Bs[wc*32      + m16][quad*8];
      bf16x8 b1 = *(const bf16x8*)&Bs[wc*32 + 16 + m16][quad*8];
      acc[0][0] = __builtin_amdgcn_mfma_f32_16x16x32_bf16(a0,b0,acc[0][0],0,0,0);
      acc[0][1] = __builtin_amdgcn_mfma_f32_16x16x32_bf16(a0,b1,acc[0][1],0,0,0);
      acc[1][0] = __builtin_amdgcn_mfma_f32_16x16x32_bf16(a1,b0,acc[1][0],0,0,0);
      acc[1][1] = __builtin_amdgcn_mfma_f32_16x16x32_bf16(a1,b1,acc[1][1],0,0,0);
      __syncthreads();
    }
    #pragma unroll
    for (int mi=0;mi<2;mi++)
      #pragma unroll
      for (int ni=0;ni<2;ni++)
        #pragma unroll
        for (int reg=0;reg<4;reg++) {
          int gm = M0 + wr*32 + mi*16 + quad*4 + reg;
          int go = N0 + wc*32 + ni*16 + m16;
          float bias = 0.f;
          if (go < 798) bias = ub[go];
          else if (go >= 800 && go < 1598) bias = wb[go-800];
          float v = (acc[mi][ni][reg] + bias) * C2F;
          uw2[gm*1600 + go] = (ushort_t)f2b(v);
        }
  } else {
    // Viterbi: 4 waves, one batch each; fp32; strict-> keeps first max like jnp.argmax
    float* em = (float*)smem;                             // [4][256][12]
    unsigned char* hist = (unsigned char*)(smem + 49152); // [4][255][16]
    const float* ner = (const float*)(ws + WS_NER);
    int* tags = (int*)(ws + WS_TAGS);
    for (int idx = tid; idx < 9216; idx += 256) {
      int bb = idx / 2304, rem = idx - bb*2304;
      int s = rem / 9, tt2 = rem - s*9;
      em[(bb*256+s)*12 + tt2] = ner[(bb*256+s)*9 + tt2];
    }
    __syncthreads();
    int w = tid>>6, lane = tid&63;
    int b = w;
    int tt = lane < 9 ? lane : 8;         // clamp: lanes>=9 compute junk, never read
    float tcol[9];
    #pragma unroll
    for (int p=0;p<9;p++) tcol[p] = trans[p*9+tt];
    float score = start_t[tt] + em[(b*256 + 0)*12 + tt];
    for (int s=1; s<256; s++) {
      float sp[9];
      #pragma unroll
      for (int p=0;p<9;p++) sp[p] = __shfl(score, p);
      float best = -3.0e38f; int arg = 0;
      #pragma unroll
      for (int p=0;p<9;p++) {
        float c = sp[p] + tcol[p];
        if (c > best) { best = c; arg = p; }
      }
      score = best + em[(b*256 + s)*12 + tt];
      if (lane < 9) hist[(b*255 + (s-1))*16 + lane] = (unsigned char)arg;
    }
    float fin = score + end_t[tt];
    float bv = -3.0e38f; int ba = 0;
    #pragma unroll
    for (int p=0;p<9;p++) {
      float v = __shfl(fin, p);
      if (v > bv) { bv = v; ba = p; }
    }
    if (lane == 0) {
      int cur = ba;
      tags[b*256 + 255] = cur;
      out_tags[b*256 + 255] = (float)cur;
      for (int k=254; k>=0; k--) {
        cur = hist[(b*255 + k)*16 + cur];
        tags[b*256 + k] = cur;
        out_tags[b*256 + k] = (float)cur;
      }
    }
  }
}

// --------------------------------------------------------------- scorer ----
// scores[b,i,j,r] = sum_h tanh(u[b,i,h]+w[b,j,h]) * V[h,r]; diag(none_idx)=100
__global__ __launch_bounds__(256) void scorer_kernel(
    char* __restrict__ ws, const int* __restrict__ none_p,
    float* __restrict__ d_out)
{
  __shared__ ushort_t su[16][808];
  __shared__ ushort_t sw[16][808];
  const ushort_t* uw2 = (const ushort_t*)(ws + WS_UW2);
  const float* lab2   = (const float*)(ws + WS_LAB2);
  const ushort_t* vf  = (const ushort_t*)(ws + WS_VFRAG);
  const int* tags     = (const int*)(ws + WS_TAGS);
  float* out_sc = d_out + 1024;
  int bx = blockIdx.x, tid = threadIdx.x;
  int b = bx >> 8, ti = (bx>>4)&15, tj = bx&15;
  int I0 = ti*16, J0 = tj*16, bS = b*256;

  for (int idx = tid; idx < 1600; idx += 256) {   // stage su = u2 + lab2[tag] (bf16)
    int row = idx / 100, c8 = idx - row*100, kc = c8*8;
    int grow = bS + I0 + row;
    int tag = tags[grow];
    i32x4 uv = *(const i32x4*)(uw2 + (size_t)grow*1600 + kc);
    const float* lp = lab2 + tag*1600 + kc;
    f32x4 l0 = *(const f32x4*)lp;
    f32x4 l1 = *(const f32x4*)(lp+4);
    i32x4 q = (i32x4){ (int)pkbf16(hi16(uv.x)+l0.y, lo16(uv.x)+l0.x),
                       (int)pkbf16(hi16(uv.y)+l0.w, lo16(uv.y)+l0.z),
                       (int)pkbf16(hi16(uv.z)+l1.y, lo16(uv.z)+l1.x),
                       (int)pkbf16(hi16(uv.w)+l1.w, lo16(uv.w)+l1.z) };
    *(i32x4*)&su[row][kc] = q;
  }
  for (int idx = tid; idx < 1600; idx += 256) {   // stage sw = w2 + lab2[tag] (bf16)
    int row = idx / 100, c8 = idx - row*100, kc = c8*8;
    int grow = bS + J0 + row;
    int tag = tags[grow];
    i32x4 uv = *(const i32x4*)(uw2 + (size_t)grow*1600 + 800 + kc);
    const float* lp = lab2 + tag*1600 + 800 + kc;
    f32x4 l0 = *(const f32x4*)lp;
    f32x4 l1 = *(const f32x4*)(lp+4);
    i32x4 q = (i32x4){ (int)pkbf16(hi16(uv.x)+l0.y, lo16(uv.x)+l0.x),
                       (int)pkbf16(hi16(uv.y)+l0.w, lo16(uv.y)+l0.z),
                       (int)pkbf16(hi16(uv.z)+l1.y, lo16(uv.z)+l1.x),
                       (int)pkbf16(hi16(uv.w)+l1.w, lo16(uv.w)+l1.z) };
    *(i32x4*)&sw[row][kc] = q;
  }
  __syncthreads();

  int lane = tid & 63, w = tid >> 6;
  int m16 = lane & 15, quad = lane >> 4;
  int none = *none_p;
  bf16x8 bf[25];                       // V B-frags, register-resident (~100 VGPR)
  #pragma unroll
  for (int c=0;c<25;c++) bf[c] = *(const bf16x8*)(vf + (c*64 + lane)*8);

  for (int it=0; it<4; it++) {
    int i = w*4 + it;                  // wave's i within the 16-row tile
    f32x4 acc = (f32x4){0.f,0.f,0.f,0.f};
    #pragma unroll
    for (int c=0;c<25;c++) {
      int koff = c*32 + quad*8;
      i32x4 uv = *(const i32x4*)&su[i][koff];     // broadcast within quad
      i32x4 wv = *(const i32x4*)&sw[m16][koff];   // lane's j row
      unsigned a0 = pkbf16(tanh_fast(hi16(uv.x)+hi16(wv.x)), tanh_fast(lo16(uv.x)+lo16(wv.x)));
      unsigned a1 = pkbf16(tanh_fast(hi16(uv.y)+hi16(wv.y)), tanh_fast(lo16(uv.y)+lo16(wv.y)));
      unsigned a2 = pkbf16(tanh_fast(hi16(uv.z)+hi16(wv.z)), tanh_fast(lo16(uv.z)+lo16(wv.z)));
      unsigned a3 = pkbf16(tanh_fast(hi16(uv.w)+hi16(wv.w)), tanh_fast(lo16(uv.w)+lo16(wv.w)));
      i32x4 avv = (i32x4){(int)a0,(int)a1,(int)a2,(int)a3};
      bf16x8 af = __builtin_bit_cast(bf16x8, avv);
      acc = __builtin_amdgcn_mfma_f32_16x16x32_bf16(af, bf[c], acc, 0,0,0);
    }
    int r = m16;                       // D: col=lane&15 -> r, row=quad*4+reg -> j_local
    if (r < 12) {
      int gi = I0 + i;
      #pragma unroll
      for (int reg=0; reg<4; reg++) {
        int gj = J0 + quad*4 + reg;
        float v = acc[reg];
        if (gi == gj && r == none) v = 100.0f;
        out_sc[(size_t)((bS + gi)*256 + gj)*12 + r] = v;
      }
    }
  }
}

extern "C" void kernel_launch(void* const* d_in, const int* in_sizes, int n_in,
                              void* d_out, int out_size, void* d_ws, size_t ws_size,
                              hipStream_t stream)
{
  const float* embed = (const float*)d_in[0];
  const float* lw    = (const float*)d_in[1];
  const float* lb    = (const float*)d_in[2];
  const float* st    = (const float*)d_in[3];
  const float* tr    = (const float*)d_in[4];
  const float* et    = (const float*)d_in[5];
  const float* lemb  = (const float*)d_in[6];
  const float* uw    = (const float*)d_in[7];
  const float* ub    = (const float*)d_in[8];
  const float* ww    = (const float*)d_in[9];
  const float* wb    = (const float*)d_in[10];
  const float* vw    = (const float*)d_in[11];
  const int* none_p  = (const int*)d_in[12];
  char* ws = (char*)d_ws;
  float* out = (float*)d_out;

  hipLaunchKernelGGL(prep_kernel, dim3(363), dim3(256), 0, stream,
                     embed, lw, lb, lemb, uw, ww, vw, ws);
  hipLaunchKernelGGL(gemm_viterbi_kernel, dim3(401), dim3(256), 0, stream,
                     embed, uw, ub, ww, wb, st, tr, et, ws, out);
  hipLaunchKernelGGL(scorer_kernel, dim3(1024), dim3(256), 0, stream,
                     ws, none_p, out);
}

// Round 6
// 222.766 us; speedup vs baseline: 1.2225x; 1.1300x over previous
//
#include <hip/hip_runtime.h>

// BERT joint NER+relation head on MI355X (gfx950).
// Inputs: fp32. Output: fp32 flat [tags(1024) | scores(3145728)].
// R6: scorer occupancy rework - 2048 blocks (8x16 tile), LDS 38.6KB (4 blk/CU),
// V-frags via global double-buffered prefetch (VGPR 160->~80), c-outer loop.

typedef unsigned short ushort_t;
typedef __attribute__((ext_vector_type(8))) short bf16x8;
typedef __attribute__((ext_vector_type(4))) float f32x4;
typedef __attribute__((ext_vector_type(4))) int i32x4;

#define C2F 2.8853900817779268f  // 2*log2(e)

// workspace offsets (bytes), all 16-aligned; total 3,400,960 B
#define WS_UW2   0u         // ushort [1024][1600] : bf16( 2log2e*(embed@[U|W] + bias) )
#define WS_NER   3276800u   // float  [1024][9]
#define WS_VFRAG 3313664u   // ushort [25][64][8]  : V as 16x16x32 B-fragments (bf16)
#define WS_LAB2  3339264u   // float  [9][1600]    : 2log2e*(label_emb@[U|W][768:])
#define WS_TAGS  3396864u   // int    [1024]

__device__ __forceinline__ unsigned f2b(float f){          // RNE, finite only
  unsigned u = __float_as_uint(f);
  return (u + 0x7FFFu + ((u>>16)&1u)) >> 16;
}
// bf16 pair via v_perm_b32 (truncation): bits[15:0]=bf16(lo), bits[31:16]=bf16(hi)
__device__ __forceinline__ unsigned pkbf16(float hi, float lo){
  return __builtin_amdgcn_perm(__float_as_uint(hi), __float_as_uint(lo), 0x07060302u);
}
__device__ __forceinline__ float lo16(int v){ return __uint_as_float(((unsigned)v)<<16); }
__device__ __forceinline__ float hi16(int v){ return __uint_as_float(((unsigned)v)&0xFFFF0000u); }
__device__ __forceinline__ float tanh_fast(float x2){  // x2 = 2*log2e*x -> tanh(x)
  float e = __builtin_amdgcn_exp2f(x2);
  float r = __builtin_amdgcn_rcpf(e + 1.0f);
  return __builtin_fmaf(-2.0f, r, 1.0f);
}

// ---------------------------------------------------------------- prep ----
// blocks [0,50): V frags; [50,306): ner rows; [306,363): lab2
__global__ __launch_bounds__(256) void prep_kernel(
    const float* __restrict__ embed, const float* __restrict__ lw,
    const float* __restrict__ lb,    const float* __restrict__ lemb,
    const float* __restrict__ uw,    const float* __restrict__ ww,
    const float* __restrict__ vw,    char* __restrict__ ws)
{
  int bx = blockIdx.x, t = threadIdx.x;
  if (bx < 50) {                         // V B-fragments: B[k=quad*8+jj][n=lane&15]
    ushort_t* vf = (ushort_t*)(ws + WS_VFRAG);
    int idx = bx*256 + t;                // < 12800
    int jj = idx & 7, lane = (idx>>3) & 63, c = idx >> 9;
    int h = c*32 + ((lane>>4)<<3) + jj;
    int n = lane & 15;
    vf[idx] = (h < 798 && n < 12) ? (ushort_t)f2b(vw[h*12 + n]) : (ushort_t)0;
  } else if (bx < 306) {                 // ner = embed@linear_w + b (one wave per row, fp32)
    float* ner = (float*)(ws + WS_NER);
    int w = t >> 6, lane = t & 63;
    int row = (bx-50)*4 + w;             // < 1024
    float acc[9];
    #pragma unroll
    for (int i=0;i<9;i++) acc[i]=0.f;
    const float* erow = embed + row*768;
    for (int kk=0; kk<12; kk++) {
      int k = kk*64 + lane;
      float e = erow[k];
      #pragma unroll
      for (int i=0;i<9;i++) acc[i] = __builtin_fmaf(e, lw[k*9+i], acc[i]);
    }
    #pragma unroll
    for (int i=0;i<9;i++) {
      float v = acc[i];
      for (int off=32; off>0; off>>=1) v += __shfl_down(v, off);
      if (lane == 0) ner[row*9+i] = v + lb[i];
    }
  } else {                               // lab2[g][n] = C2 * (label_emb[g] @ [U|W][768:798, n])
    float* lab2 = (float*)(ws + WS_LAB2);
    int idx = (bx-306)*256 + t;
    if (idx < 14400) {
      int g = idx / 1600, n = idx - g*1600;
      const float* X = (n < 800) ? uw : ww;
      int nn = (n < 800) ? n : (n - 800);
      float v = 0.f;
      if (nn < 798) {
        float s = 0.f;
        for (int l=0;l<30;l++)
          s = __builtin_fmaf(lemb[g*30+l], X[(768+l)*798 + nn], s);
        v = s * C2F;
      }
      lab2[idx] = v;
    }
  }
}

// ------------------------------------------- fused GEMM (blocks 0..399) + Viterbi (block 400)
__global__ __launch_bounds__(256) void gemm_viterbi_kernel(
    const float* __restrict__ embed,
    const float* __restrict__ uw,    const float* __restrict__ ub,
    const float* __restrict__ ww,    const float* __restrict__ wb,
    const float* __restrict__ start_t, const float* __restrict__ trans,
    const float* __restrict__ end_t,
    char* __restrict__ ws, float* __restrict__ out_tags)
{
  __shared__ char smem[65472];           // union: GEMM tiles (10.5KB) / Viterbi em+hist (63.9KB)
  int bx = blockIdx.x, tid = threadIdx.x;
  if (bx < 400) {
    // uw2[1024][1600] = bf16( C2 * (embed[1024,768] @ [U_w|W_w][768,1600] + bias) )
    ushort_t (*As)[40] = (ushort_t(*)[40])smem;            // [m][k] +8 pad, 5120 B
    ushort_t (*Bs)[42] = (ushort_t(*)[42])(smem + 5120);   // [n][k] +10 pad, 5376 B
    ushort_t* uw2 = (ushort_t*)(ws + WS_UW2);
    int bm = bx & 15, bn = bx >> 4;
    int M0 = bm*64, N0 = bn*64;
    int w = tid>>6, lane = tid&63;
    int wr = w>>1, wc = w&1;
    int m16 = lane&15, quad = lane>>4;
    // A staging coords: row nl, 8-k chunk k8
    int nl = tid>>2, k8 = (tid&3)<<3;
    // B staging coords: column n (coalesced lanes), k-pair per wave
    int bnn = tid & 63, bw = tid >> 6;
    int gn = N0 + bnn;
    const float* bsrc = uw; int bcol = 0; bool bzero = true;
    if (gn < 798)                    { bsrc = uw; bcol = gn;     bzero = false; }
    else if (gn >= 800 && gn < 1598) { bsrc = ww; bcol = gn-800; bzero = false; }

    f32x4 acc[2][2];
    #pragma unroll
    for (int mi=0;mi<2;mi++)
      #pragma unroll
      for (int ni=0;ni<2;ni++) acc[mi][ni] = (f32x4){0.f,0.f,0.f,0.f};

    // ---- register prefetch for k0=0
    f32x4 a_lo, a_hi; float bvals[8];
    {
      const float* ap = &embed[(M0+nl)*768 + k8];
      a_lo = *(const f32x4*)ap; a_hi = *(const f32x4*)(ap+4);
      #pragma unroll
      for (int r=0;r<4;r++) {
        int kk = r*8 + bw*2;
        bvals[2*r]   = bzero ? 0.f : bsrc[(kk  )*798 + bcol];
        bvals[2*r+1] = bzero ? 0.f : bsrc[(kk+1)*798 + bcol];
      }
    }
    for (int k0=0; k0<768; k0+=32) {
      // commit prefetched tile to LDS
      i32x4 av = (i32x4){ (int)pkbf16(a_lo.y,a_lo.x), (int)pkbf16(a_lo.w,a_lo.z),
                          (int)pkbf16(a_hi.y,a_hi.x), (int)pkbf16(a_hi.w,a_hi.z) };
      *(i32x4*)&As[nl][k8] = av;
      #pragma unroll
      for (int r=0;r<4;r++) {
        int kk = r*8 + bw*2;
        *(unsigned*)&Bs[bnn][kk] = pkbf16(bvals[2*r+1], bvals[2*r]);
      }
      __syncthreads();
      // prefetch next tile while MFMA phase runs
      if (k0 + 32 < 768) {
        const float* ap = &embed[(M0+nl)*768 + k0 + 32 + k8];
        a_lo = *(const f32x4*)ap; a_hi = *(const f32x4*)(ap+4);
        #pragma unroll
        for (int r=0;r<4;r++) {
          int kk = r*8 + bw*2;
          bvals[2*r]   = bzero ? 0.f : bsrc[(k0+32+kk  )*798 + bcol];
          bvals[2*r+1] = bzero ? 0.f : bsrc[(k0+32+kk+1)*798 + bcol];
        }
      }
      bf16x8 a0 = *(const bf16x8*)&As[wr*32      + m16][quad*8];
      bf16x8 a1 = *(const bf16x8*)&As[wr*32 + 16 + m16][quad*8];
      bf16x8 b0 = *(const bf16x8*)&Bs[wc*32      + m16][quad*8];
      bf16x8 b1 = *(const bf16x8*)&Bs[wc*32 + 16 + m16][quad*8];
      acc[0][0] = __builtin_amdgcn_mfma_f32_16x16x32_bf16(a0,b0,acc[0][0],0,0,0);
      acc[0][1] = __builtin_amdgcn_mfma_f32_16x16x32_bf16(a0,b1,acc[0][1],0,0,0);
      acc[1][0] = __builtin_amdgcn_mfma_f32_16x16x32_bf16(a1,b0,acc[1][0],0,0,0);
      acc[1][1] = __builtin_amdgcn_mfma_f32_16x16x32_bf16(a1,b1,acc[1][1],0,0,0);
      __syncthreads();
    }
    #pragma unroll
    for (int mi=0;mi<2;mi++)
      #pragma unroll
      for (int ni=0;ni<2;ni++)
        #pragma unroll
        for (int reg=0;reg<4;reg++) {
          int gm = M0 + wr*32 + mi*16 + quad*4 + reg;
          int go = N0 + wc*32 + ni*16 + m16;
          float bias = 0.f;
          if (go < 798) bias = ub[go];
          else if (go >= 800 && go < 1598) bias = wb[go-800];
          float v = (acc[mi][ni][reg] + bias) * C2F;
          uw2[gm*1600 + go] = (ushort_t)f2b(v);
        }
  } else {
    // Viterbi: 4 waves, one batch each; fp32; strict-> keeps first max like jnp.argmax
    float* em = (float*)smem;                             // [4][256][12]
    unsigned char* hist = (unsigned char*)(smem + 49152); // [4][255][16]
    const float* ner = (const float*)(ws + WS_NER);
    int* tags = (int*)(ws + WS_TAGS);
    for (int idx = tid; idx < 9216; idx += 256) {
      int bb = idx / 2304, rem = idx - bb*2304;
      int s = rem / 9, tt2 = rem - s*9;
      em[(bb*256+s)*12 + tt2] = ner[(bb*256+s)*9 + tt2];
    }
    __syncthreads();
    int w = tid>>6, lane = tid&63;
    int b = w;
    int tt = lane < 9 ? lane : 8;         // clamp: lanes>=9 compute junk, never read
    float tcol[9];
    #pragma unroll
    for (int p=0;p<9;p++) tcol[p] = trans[p*9+tt];
    float score = start_t[tt] + em[(b*256 + 0)*12 + tt];
    for (int s=1; s<256; s++) {
      float sp[9];
      #pragma unroll
      for (int p=0;p<9;p++) sp[p] = __shfl(score, p);
      float best = -3.0e38f; int arg = 0;
      #pragma unroll
      for (int p=0;p<9;p++) {
        float c = sp[p] + tcol[p];
        if (c > best) { best = c; arg = p; }
      }
      score = best + em[(b*256 + s)*12 + tt];
      if (lane < 9) hist[(b*255 + (s-1))*16 + lane] = (unsigned char)arg;
    }
    float fin = score + end_t[tt];
    float bv = -3.0e38f; int ba = 0;
    #pragma unroll
    for (int p=0;p<9;p++) {
      float v = __shfl(fin, p);
      if (v > bv) { bv = v; ba = p; }
    }
    if (lane == 0) {
      int cur = ba;
      tags[b*256 + 255] = cur;
      out_tags[b*256 + 255] = (float)cur;
      for (int k=254; k>=0; k--) {
        cur = hist[(b*255 + k)*16 + cur];
        tags[b*256 + k] = cur;
        out_tags[b*256 + k] = (float)cur;
      }
    }
  }
}

// --------------------------------------------------------------- scorer ----
// scores[b,i,j,r] = sum_h tanh(u[b,i,h]+w[b,j,h]) * V[h,r]; diag(none_idx)=100
// 2048 blocks: 8 i-rows x 16 j-rows per block. LDS 38.6KB -> 4 blocks/CU.
__global__ __launch_bounds__(256) void scorer_kernel(
    char* __restrict__ ws, const int* __restrict__ none_p,
    float* __restrict__ d_out)
{
  __shared__ ushort_t su[8][804];    // stride 804: 18*m16 mod 32 -> 16 distinct banks
  __shared__ ushort_t sw[16][804];
  const ushort_t* uw2 = (const ushort_t*)(ws + WS_UW2);
  const float* lab2   = (const float*)(ws + WS_LAB2);
  const ushort_t* vf  = (const ushort_t*)(ws + WS_VFRAG);
  const int* tags     = (const int*)(ws + WS_TAGS);
  float* out_sc = d_out + 1024;
  int bx = blockIdx.x, tid = threadIdx.x;
  int b = bx >> 9, ti = (bx>>4)&31, tj = bx&15;
  int I0 = ti*8, J0 = tj*16, bS = b*256;

  for (int idx = tid; idx < 800; idx += 256) {    // stage su = u2 + lab2[tag] (bf16)
    int row = idx / 100, c8 = idx - row*100, kc = c8*8;
    int grow = bS + I0 + row;
    int tag = tags[grow];
    i32x4 uv = *(const i32x4*)(uw2 + (size_t)grow*1600 + kc);
    const float* lp = lab2 + tag*1600 + kc;
    f32x4 l0 = *(const f32x4*)lp;
    f32x4 l1 = *(const f32x4*)(lp+4);
    i32x4 q = (i32x4){ (int)pkbf16(hi16(uv.x)+l0.y, lo16(uv.x)+l0.x),
                       (int)pkbf16(hi16(uv.y)+l0.w, lo16(uv.y)+l0.z),
                       (int)pkbf16(hi16(uv.z)+l1.y, lo16(uv.z)+l1.x),
                       (int)pkbf16(hi16(uv.w)+l1.w, lo16(uv.w)+l1.z) };
    *(i32x4*)&su[row][kc] = q;
  }
  for (int idx = tid; idx < 1600; idx += 256) {   // stage sw = w2 + lab2[tag] (bf16)
    int row = idx / 100, c8 = idx - row*100, kc = c8*8;
    int grow = bS + J0 + row;
    int tag = tags[grow];
    i32x4 uv = *(const i32x4*)(uw2 + (size_t)grow*1600 + 800 + kc);
    const float* lp = lab2 + tag*1600 + 800 + kc;
    f32x4 l0 = *(const f32x4*)lp;
    f32x4 l1 = *(const f32x4*)(lp+4);
    i32x4 q = (i32x4){ (int)pkbf16(hi16(uv.x)+l0.y, lo16(uv.x)+l0.x),
                       (int)pkbf16(hi16(uv.y)+l0.w, lo16(uv.y)+l0.z),
                       (int)pkbf16(hi16(uv.z)+l1.y, lo16(uv.z)+l1.x),
                       (int)pkbf16(hi16(uv.w)+l1.w, lo16(uv.w)+l1.z) };
    *(i32x4*)&sw[row][kc] = q;
  }
  __syncthreads();

  int lane = tid & 63, w = tid >> 6;
  int m16 = lane & 15, quad = lane >> 4;
  int none = *none_p;

  f32x4 acc[2];
  acc[0] = (f32x4){0.f,0.f,0.f,0.f};
  acc[1] = (f32x4){0.f,0.f,0.f,0.f};

  const ushort_t* vlane = vf + lane*8;            // V frag stream, stride 1024B per c
  i32x4 bfc = *(const i32x4*)vlane;               // c=0
  for (int c=0; c<25; c++) {
    i32x4 bfn;
    if (c < 24) bfn = *(const i32x4*)(vlane + (c+1)*512);
    int koff = c*32 + quad*8;
    i32x4 wv = *(const i32x4*)&sw[m16][koff];     // lane's j row (per c)
    bf16x8 bfrag = __builtin_bit_cast(bf16x8, bfc);
    #pragma unroll
    for (int it=0; it<2; it++) {
      i32x4 uv = *(const i32x4*)&su[w*2+it][koff];  // quad-broadcast
      unsigned a0 = pkbf16(tanh_fast(hi16(uv.x)+hi16(wv.x)), tanh_fast(lo16(uv.x)+lo16(wv.x)));
      unsigned a1 = pkbf16(tanh_fast(hi16(uv.y)+hi16(wv.y)), tanh_fast(lo16(uv.y)+lo16(wv.y)));
      unsigned a2 = pkbf16(tanh_fast(hi16(uv.z)+hi16(wv.z)), tanh_fast(lo16(uv.z)+lo16(wv.z)));
      unsigned a3 = pkbf16(tanh_fast(hi16(uv.w)+hi16(wv.w)), tanh_fast(lo16(uv.w)+lo16(wv.w)));
      i32x4 avv = (i32x4){(int)a0,(int)a1,(int)a2,(int)a3};
      bf16x8 af = __builtin_bit_cast(bf16x8, avv);
      acc[it] = __builtin_amdgcn_mfma_f32_16x16x32_bf16(af, bfrag, acc[it], 0,0,0);
    }
    bfc = bfn;
  }

  int r = m16;                         // D: col=lane&15 -> r, row=quad*4+reg -> j_local
  if (r < 12) {
    #pragma unroll
    for (int it=0; it<2; it++) {
      int gi = I0 + w*2 + it;
      #pragma unroll
      for (int reg=0; reg<4; reg++) {
        int gj = J0 + quad*4 + reg;
        float v = acc[it][reg];
        if (gi == gj && r == none) v = 100.0f;
        out_sc[(size_t)((bS + gi)*256 + gj)*12 + r] = v;
      }
    }
  }
}

extern "C" void kernel_launch(void* const* d_in, const int* in_sizes, int n_in,
                              void* d_out, int out_size, void* d_ws, size_t ws_size,
                              hipStream_t stream)
{
  const float* embed = (const float*)d_in[0];
  const float* lw    = (const float*)d_in[1];
  const float* lb    = (const float*)d_in[2];
  const float* st    = (const float*)d_in[3];
  const float* tr    = (const float*)d_in[4];
  const float* et    = (const float*)d_in[5];
  const float* lemb  = (const float*)d_in[6];
  const float* uw    = (const float*)d_in[7];
  const float* ub    = (const float*)d_in[8];
  const float* ww    = (const float*)d_in[9];
  const float* wb    = (const float*)d_in[10];
  const float* vw    = (const float*)d_in[11];
  const int* none_p  = (const int*)d_in[12];
  char* ws = (char*)d_ws;
  float* out = (float*)d_out;

  hipLaunchKernelGGL(prep_kernel, dim3(363), dim3(256), 0, stream,
                     embed, lw, lb, lemb, uw, ww, vw, ws);
  hipLaunchKernelGGL(gemm_viterbi_kernel, dim3(401), dim3(256), 0, stream,
                     embed, uw, ub, ww, wb, st, tr, et, ws, out);
  hipLaunchKernelGGL(scorer_kernel, dim3(2048), dim3(256), 0, stream,
                     ws, none_p, out);
}

// Round 7
// 218.146 us; speedup vs baseline: 1.2484x; 1.0212x over previous
//
#include <hip/hip_runtime.h>

// BERT joint NER+relation head on MI355X (gfx950).
// Inputs: fp32. Output: fp32 flat [tags(1024) | scores(3145728)].
// R7: Viterbi restructured - readlane forward pass (no argmax in loop),
// parallel hist post-pass, suffix-scan backtrace (no serial LDS chase).

typedef unsigned short ushort_t;
typedef __attribute__((ext_vector_type(8))) short bf16x8;
typedef __attribute__((ext_vector_type(4))) float f32x4;
typedef __attribute__((ext_vector_type(4))) int i32x4;

#define C2F 2.8853900817779268f  // 2*log2(e)

// workspace offsets (bytes), all 16-aligned; total 3,400,960 B
#define WS_UW2   0u         // ushort [1024][1600] : bf16( 2log2e*(embed@[U|W] + bias) )
#define WS_NER   3276800u   // float  [1024][9]
#define WS_VFRAG 3313664u   // ushort [25][64][8]  : V as 16x16x32 B-fragments (bf16)
#define WS_LAB2  3339264u   // float  [9][1600]    : 2log2e*(label_emb@[U|W][768:])
#define WS_TAGS  3396864u   // int    [1024]

__device__ __forceinline__ unsigned f2b(float f){          // RNE, finite only
  unsigned u = __float_as_uint(f);
  return (u + 0x7FFFu + ((u>>16)&1u)) >> 16;
}
// bf16 pair via v_perm_b32 (truncation): bits[15:0]=bf16(lo), bits[31:16]=bf16(hi)
__device__ __forceinline__ unsigned pkbf16(float hi, float lo){
  return __builtin_amdgcn_perm(__float_as_uint(hi), __float_as_uint(lo), 0x07060302u);
}
__device__ __forceinline__ float lo16(int v){ return __uint_as_float(((unsigned)v)<<16); }
__device__ __forceinline__ float hi16(int v){ return __uint_as_float(((unsigned)v)&0xFFFF0000u); }
__device__ __forceinline__ float tanh_fast(float x2){  // x2 = 2*log2e*x -> tanh(x)
  float e = __builtin_amdgcn_exp2f(x2);
  float r = __builtin_amdgcn_rcpf(e + 1.0f);
  return __builtin_fmaf(-2.0f, r, 1.0f);
}

// ---------------------------------------------------------------- prep ----
// blocks [0,50): V frags; [50,306): ner rows; [306,363): lab2
__global__ __launch_bounds__(256) void prep_kernel(
    const float* __restrict__ embed, const float* __restrict__ lw,
    const float* __restrict__ lb,    const float* __restrict__ lemb,
    const float* __restrict__ uw,    const float* __restrict__ ww,
    const float* __restrict__ vw,    char* __restrict__ ws)
{
  int bx = blockIdx.x, t = threadIdx.x;
  if (bx < 50) {                         // V B-fragments: B[k=quad*8+jj][n=lane&15]
    ushort_t* vf = (ushort_t*)(ws + WS_VFRAG);
    int idx = bx*256 + t;                // < 12800
    int jj = idx & 7, lane = (idx>>3) & 63, c = idx >> 9;
    int h = c*32 + ((lane>>4)<<3) + jj;
    int n = lane & 15;
    vf[idx] = (h < 798 && n < 12) ? (ushort_t)f2b(vw[h*12 + n]) : (ushort_t)0;
  } else if (bx < 306) {                 // ner = embed@linear_w + b (one wave per row, fp32)
    float* ner = (float*)(ws + WS_NER);
    int w = t >> 6, lane = t & 63;
    int row = (bx-50)*4 + w;             // < 1024
    float acc[9];
    #pragma unroll
    for (int i=0;i<9;i++) acc[i]=0.f;
    const float* erow = embed + row*768;
    for (int kk=0; kk<12; kk++) {
      int k = kk*64 + lane;
      float e = erow[k];
      #pragma unroll
      for (int i=0;i<9;i++) acc[i] = __builtin_fmaf(e, lw[k*9+i], acc[i]);
    }
    #pragma unroll
    for (int i=0;i<9;i++) {
      float v = acc[i];
      for (int off=32; off>0; off>>=1) v += __shfl_down(v, off);
      if (lane == 0) ner[row*9+i] = v + lb[i];
    }
  } else {                               // lab2[g][n] = C2 * (label_emb[g] @ [U|W][768:798, n])
    float* lab2 = (float*)(ws + WS_LAB2);
    int idx = (bx-306)*256 + t;
    if (idx < 14400) {
      int g = idx / 1600, n = idx - g*1600;
      const float* X = (n < 800) ? uw : ww;
      int nn = (n < 800) ? n : (n - 800);
      float v = 0.f;
      if (nn < 798) {
        float s = 0.f;
        for (int l=0;l<30;l++)
          s = __builtin_fmaf(lemb[g*30+l], X[(768+l)*798 + nn], s);
        v = s * C2F;
      }
      lab2[idx] = v;
    }
  }
}

// ------------------------------------------- fused GEMM (blocks 0..399) + Viterbi (block 400)
__global__ __launch_bounds__(256) void gemm_viterbi_kernel(
    const float* __restrict__ embed,
    const float* __restrict__ uw,    const float* __restrict__ ub,
    const float* __restrict__ ww,    const float* __restrict__ wb,
    const float* __restrict__ start_t, const float* __restrict__ trans,
    const float* __restrict__ end_t,
    char* __restrict__ ws, float* __restrict__ out_tags)
{
  __shared__ char smem[65472];           // union: GEMM tiles (10.5KB) / Viterbi (55.3KB)
  int bx = blockIdx.x, tid = threadIdx.x;
  if (bx < 400) {
    // uw2[1024][1600] = bf16( C2 * (embed[1024,768] @ [U_w|W_w][768,1600] + bias) )
    ushort_t (*As)[40] = (ushort_t(*)[40])smem;            // [m][k] +8 pad, 5120 B
    ushort_t (*Bs)[42] = (ushort_t(*)[42])(smem + 5120);   // [n][k] +10 pad, 5376 B
    ushort_t* uw2 = (ushort_t*)(ws + WS_UW2);
    int bm = bx & 15, bn = bx >> 4;
    int M0 = bm*64, N0 = bn*64;
    int w = tid>>6, lane = tid&63;
    int wr = w>>1, wc = w&1;
    int m16 = lane&15, quad = lane>>4;
    // A staging coords: row nl, 8-k chunk k8
    int nl = tid>>2, k8 = (tid&3)<<3;
    // B staging coords: column n (coalesced lanes), k-pair per wave
    int bnn = tid & 63, bw = tid >> 6;
    int gn = N0 + bnn;
    const float* bsrc = uw; int bcol = 0; bool bzero = true;
    if (gn < 798)                    { bsrc = uw; bcol = gn;     bzero = false; }
    else if (gn >= 800 && gn < 1598) { bsrc = ww; bcol = gn-800; bzero = false; }

    f32x4 acc[2][2];
    #pragma unroll
    for (int mi=0;mi<2;mi++)
      #pragma unroll
      for (int ni=0;ni<2;ni++) acc[mi][ni] = (f32x4){0.f,0.f,0.f,0.f};

    // ---- register prefetch for k0=0
    f32x4 a_lo, a_hi; float bvals[8];
    {
      const float* ap = &embed[(M0+nl)*768 + k8];
      a_lo = *(const f32x4*)ap; a_hi = *(const f32x4*)(ap+4);
      #pragma unroll
      for (int r=0;r<4;r++) {
        int kk = r*8 + bw*2;
        bvals[2*r]   = bzero ? 0.f : bsrc[(kk  )*798 + bcol];
        bvals[2*r+1] = bzero ? 0.f : bsrc[(kk+1)*798 + bcol];
      }
    }
    for (int k0=0; k0<768; k0+=32) {
      // commit prefetched tile to LDS
      i32x4 av = (i32x4){ (int)pkbf16(a_lo.y,a_lo.x), (int)pkbf16(a_lo.w,a_lo.z),
                          (int)pkbf16(a_hi.y,a_hi.x), (int)pkbf16(a_hi.w,a_hi.z) };
      *(i32x4*)&As[nl][k8] = av;
      #pragma unroll
      for (int r=0;r<4;r++) {
        int kk = r*8 + bw*2;
        *(unsigned*)&Bs[bnn][kk] = pkbf16(bvals[2*r+1], bvals[2*r]);
      }
      __syncthreads();
      // prefetch next tile while MFMA phase runs
      if (k0 + 32 < 768) {
        const float* ap = &embed[(M0+nl)*768 + k0 + 32 + k8];
        a_lo = *(const f32x4*)ap; a_hi = *(const f32x4*)(ap+4);
        #pragma unroll
        for (int r=0;r<4;r++) {
          int kk = r*8 + bw*2;
          bvals[2*r]   = bzero ? 0.f : bsrc[(k0+32+kk  )*798 + bcol];
          bvals[2*r+1] = bzero ? 0.f : bsrc[(k0+32+kk+1)*798 + bcol];
        }
      }
      bf16x8 a0 = *(const bf16x8*)&As[wr*32      + m16][quad*8];
      bf16x8 a1 = *(const bf16x8*)&As[wr*32 + 16 + m16][quad*8];
      bf16x8 b0 = *(const bf16x8*)&Bs[wc*32      + m16][quad*8];
      bf16x8 b1 = *(const bf16x8*)&Bs[wc*32 + 16 + m16][quad*8];
      acc[0][0] = __builtin_amdgcn_mfma_f32_16x16x32_bf16(a0,b0,acc[0][0],0,0,0);
      acc[0][1] = __builtin_amdgcn_mfma_f32_16x16x32_bf16(a0,b1,acc[0][1],0,0,0);
      acc[1][0] = __builtin_amdgcn_mfma_f32_16x16x32_bf16(a1,b0,acc[1][0],0,0,0);
      acc[1][1] = __builtin_amdgcn_mfma_f32_16x16x32_bf16(a1,b1,acc[1][1],0,0,0);
      __syncthreads();
    }
    #pragma unroll
    for (int mi=0;mi<2;mi++)
      #pragma unroll
      for (int ni=0;ni<2;ni++)
        #pragma unroll
        for (int reg=0;reg<4;reg++) {
          int gm = M0 + wr*32 + mi*16 + quad*4 + reg;
          int go = N0 + wc*32 + ni*16 + m16;
          float bias = 0.f;
          if (go < 798) bias = ub[go];
          else if (go >= 800 && go < 1598) bias = wb[go-800];
          float v = (acc[mi][ni][reg] + bias) * C2F;
          uw2[gm*1600 + go] = (ushort_t)f2b(v);
        }
  } else {
    // ---- Viterbi, restructured ----
    // LDS: scores[4][256][9] f32 (36864B) | bufA[4][255][9] u8 (9180B @36864)
    //      bufB[4][255][9] u8 (@46048)    | trl[81] f32 (aliases bufB)
    //      lastArr[4] int (@55232)
    float* scores = (float*)smem;
    unsigned char* bufA = (unsigned char*)(smem + 36864);
    unsigned char* bufB = (unsigned char*)(smem + 46048);
    float* trl = (float*)(smem + 46048);          // staged trans, dead after round d=1
    int* lastArr = (int*)(smem + 55232);
    const float* ner = (const float*)(ws + WS_NER);
    int* tags = (int*)(ws + WS_TAGS);

    int w = tid>>6, lane = tid&63;
    int b = w;
    int tt = lane < 9 ? lane : 8;       // lanes 9..63 mirror lane 8 (same data, same addr)
    if (tid < 81) trl[tid] = trans[tid];

    float tcol[9];
    #pragma unroll
    for (int p=0;p<9;p++) tcol[p] = trans[p*9+tt];
    const float* nb = ner + (b*256)*9 + tt;

    float score = start_t[tt] + nb[0];
    scores[(b*256 + 0)*9 + tt] = score;

    // forward: 255 steps = 17 chunks x 15, em register-prefetched
    float cur[15], nxt[15];
    #pragma unroll
    for (int j=0;j<15;j++) cur[j] = nb[(1+j)*9];
    #define RL(p) (__uint_as_float(__builtin_amdgcn_readlane(__float_as_uint(score), p)) + tcol[p])
    for (int ch=0; ch<17; ch++) {
      int sb = 1 + ch*15;
      if (ch < 16) {
        #pragma unroll
        for (int j=0;j<15;j++) nxt[j] = nb[(sb+15+j)*9];
      }
      #pragma unroll
      for (int j=0;j<15;j++) {
        float m0 = fmaxf(fmaxf(RL(0),RL(1)),RL(2));
        float m1 = fmaxf(fmaxf(RL(3),RL(4)),RL(5));
        float m2 = fmaxf(fmaxf(RL(6),RL(7)),RL(8));
        score = fmaxf(fmaxf(m0,m1),m2) + cur[j];
        scores[(b*256 + sb + j)*9 + tt] = score;
      }
      #pragma unroll
      for (int j=0;j<15;j++) cur[j] = nxt[j];
    }
    // last tag per batch (first-max over fin, uniform across wave)
    {
      float fin = score + end_t[tt];
      #define RLF(p) __uint_as_float(__builtin_amdgcn_readlane(__float_as_uint(fin), p))
      float bv = RLF(0); int ba = 0;
      #pragma unroll
      for (int p=1;p<9;p++) { float v = RLF(p); if (v > bv) { bv = v; ba = p; } }
      if (lane == 0) lastArr[b] = ba;
      #undef RLF
    }
    #undef RL
    __syncthreads();

    // hist post-pass: funcs[b][s][t] = argmax_p(scores[b][s][p] + trans[p][t]), s in [0,254]
    for (int idx = tid; idx < 9180; idx += 256) {
      int bb = idx / 2295, r = idx - bb*2295;
      int s = r / 9, t = r - s*9;
      const float* srow = &scores[(bb*256 + s)*9];
      float best = srow[0] + trl[t]; int arg = 0;
      #pragma unroll
      for (int p=1;p<9;p++) {
        float v = srow[p] + trl[p*9 + t];
        if (v > best) { best = v; arg = p; }
      }
      bufA[idx] = (unsigned char)arg;
    }
    __syncthreads();

    // suffix scan of function composition: F_s <- F_s o F_{s+d}
    unsigned char* curb = bufA; unsigned char* nxtb = bufB;
    for (int d=1; d<255; d<<=1) {
      for (int idx = tid; idx < 9180; idx += 256) {
        int bb = idx / 2295, r = idx - bb*2295;
        int s = r / 9, t = r - s*9;
        unsigned char v;
        if (s + d <= 254) {
          unsigned char tm = curb[bb*2295 + (s+d)*9 + t];
          v = curb[bb*2295 + s*9 + tm];
        } else v = curb[idx];
        nxtb[idx] = v;
      }
      __syncthreads();
      unsigned char* tmp = curb; curb = nxtb; nxtb = tmp;
    }
    // 8 rounds -> result back in bufA (curb)

    for (int idx = tid; idx < 1024; idx += 256) {
      int bb = idx >> 8, s = idx & 255;
      int last = lastArr[bb];
      int tg = (s == 255) ? last : (int)curb[bb*2295 + s*9 + last];
      tags[idx] = tg;
      out_tags[idx] = (float)tg;
    }
  }
}

// --------------------------------------------------------------- scorer ----
// scores[b,i,j,r] = sum_h tanh(u[b,i,h]+w[b,j,h]) * V[h,r]; diag(none_idx)=100
// 2048 blocks: 8 i-rows x 16 j-rows per block. LDS 38.6KB -> 4 blocks/CU.
__global__ __launch_bounds__(256) void scorer_kernel(
    char* __restrict__ ws, const int* __restrict__ none_p,
    float* __restrict__ d_out)
{
  __shared__ ushort_t su[8][804];    // stride 804: 18*m16 mod 32 -> 16 distinct banks
  __shared__ ushort_t sw[16][804];
  const ushort_t* uw2 = (const ushort_t*)(ws + WS_UW2);
  const float* lab2   = (const float*)(ws + WS_LAB2);
  const ushort_t* vf  = (const ushort_t*)(ws + WS_VFRAG);
  const int* tags     = (const int*)(ws + WS_TAGS);
  float* out_sc = d_out + 1024;
  int bx = blockIdx.x, tid = threadIdx.x;
  int b = bx >> 9, ti = (bx>>4)&31, tj = bx&15;
  int I0 = ti*8, J0 = tj*16, bS = b*256;

  for (int idx = tid; idx < 800; idx += 256) {    // stage su = u2 + lab2[tag] (bf16)
    int row = idx / 100, c8 = idx - row*100, kc = c8*8;
    int grow = bS + I0 + row;
    int tag = tags[grow];
    i32x4 uv = *(const i32x4*)(uw2 + (size_t)grow*1600 + kc);
    const float* lp = lab2 + tag*1600 + kc;
    f32x4 l0 = *(const f32x4*)lp;
    f32x4 l1 = *(const f32x4*)(lp+4);
    i32x4 q = (i32x4){ (int)pkbf16(hi16(uv.x)+l0.y, lo16(uv.x)+l0.x),
                       (int)pkbf16(hi16(uv.y)+l0.w, lo16(uv.y)+l0.z),
                       (int)pkbf16(hi16(uv.z)+l1.y, lo16(uv.z)+l1.x),
                       (int)pkbf16(hi16(uv.w)+l1.w, lo16(uv.w)+l1.z) };
    *(i32x4*)&su[row][kc] = q;
  }
  for (int idx = tid; idx < 1600; idx += 256) {   // stage sw = w2 + lab2[tag] (bf16)
    int row = idx / 100, c8 = idx - row*100, kc = c8*8;
    int grow = bS + J0 + row;
    int tag = tags[grow];
    i32x4 uv = *(const i32x4*)(uw2 + (size_t)grow*1600 + 800 + kc);
    const float* lp = lab2 + tag*1600 + 800 + kc;
    f32x4 l0 = *(const f32x4*)lp;
    f32x4 l1 = *(const f32x4*)(lp+4);
    i32x4 q = (i32x4){ (int)pkbf16(hi16(uv.x)+l0.y, lo16(uv.x)+l0.x),
                       (int)pkbf16(hi16(uv.y)+l0.w, lo16(uv.y)+l0.z),
                       (int)pkbf16(hi16(uv.z)+l1.y, lo16(uv.z)+l1.x),
                       (int)pkbf16(hi16(uv.w)+l1.w, lo16(uv.w)+l1.z) };
    *(i32x4*)&sw[row][kc] = q;
  }
  __syncthreads();

  int lane = tid & 63, w = tid >> 6;
  int m16 = lane & 15, quad = lane >> 4;
  int none = *none_p;

  f32x4 acc[2];
  acc[0] = (f32x4){0.f,0.f,0.f,0.f};
  acc[1] = (f32x4){0.f,0.f,0.f,0.f};

  const ushort_t* vlane = vf + lane*8;            // V frag stream, stride 1024B per c
  i32x4 bfc = *(const i32x4*)vlane;               // c=0
  for (int c=0; c<25; c++) {
    i32x4 bfn;
    if (c < 24) bfn = *(const i32x4*)(vlane + (c+1)*512);
    int koff = c*32 + quad*8;
    i32x4 wv = *(const i32x4*)&sw[m16][koff];     // lane's j row (per c)
    bf16x8 bfrag = __builtin_bit_cast(bf16x8, bfc);
    #pragma unroll
    for (int it=0; it<2; it++) {
      i32x4 uv = *(const i32x4*)&su[w*2+it][koff];  // quad-broadcast
      unsigned a0 = pkbf16(tanh_fast(hi16(uv.x)+hi16(wv.x)), tanh_fast(lo16(uv.x)+lo16(wv.x)));
      unsigned a1 = pkbf16(tanh_fast(hi16(uv.y)+hi16(wv.y)), tanh_fast(lo16(uv.y)+lo16(wv.y)));
      unsigned a2 = pkbf16(tanh_fast(hi16(uv.z)+hi16(wv.z)), tanh_fast(lo16(uv.z)+lo16(wv.z)));
      unsigned a3 = pkbf16(tanh_fast(hi16(uv.w)+hi16(wv.w)), tanh_fast(lo16(uv.w)+lo16(wv.w)));
      i32x4 avv = (i32x4){(int)a0,(int)a1,(int)a2,(int)a3};
      bf16x8 af = __builtin_bit_cast(bf16x8, avv);
      acc[it] = __builtin_amdgcn_mfma_f32_16x16x32_bf16(af, bfrag, acc[it], 0,0,0);
    }
    bfc = bfn;
  }

  int r = m16;                         // D: col=lane&15 -> r, row=quad*4+reg -> j_local
  if (r < 12) {
    #pragma unroll
    for (int it=0; it<2; it++) {
      int gi = I0 + w*2 + it;
      #pragma unroll
      for (int reg=0; reg<4; reg++) {
        int gj = J0 + quad*4 + reg;
        float v = acc[it][reg];
        if (gi == gj && r == none) v = 100.0f;
        out_sc[(size_t)((bS + gi)*256 + gj)*12 + r] = v;
      }
    }
  }
}

extern "C" void kernel_launch(void* const* d_in, const int* in_sizes, int n_in,
                              void* d_out, int out_size, void* d_ws, size_t ws_size,
                              hipStream_t stream)
{
  const float* embed = (const float*)d_in[0];
  const float* lw    = (const float*)d_in[1];
  const float* lb    = (const float*)d_in[2];
  const float* st    = (const float*)d_in[3];
  const float* tr    = (const float*)d_in[4];
  const float* et    = (const float*)d_in[5];
  const float* lemb  = (const float*)d_in[6];
  const float* uw    = (const float*)d_in[7];
  const float* ub    = (const float*)d_in[8];
  const float* ww    = (const float*)d_in[9];
  const float* wb    = (const float*)d_in[10];
  const float* vw    = (const float*)d_in[11];
  const int* none_p  = (const int*)d_in[12];
  char* ws = (char*)d_ws;
  float* out = (float*)d_out;

  hipLaunchKernelGGL(prep_kernel, dim3(363), dim3(256), 0, stream,
                     embed, lw, lb, lemb, uw, ww, vw, ws);
  hipLaunchKernelGGL(gemm_viterbi_kernel, dim3(401), dim3(256), 0, stream,
                     embed, uw, ub, ww, wb, st, tr, et, ws, out);
  hipLaunchKernelGGL(scorer_kernel, dim3(2048), dim3(256), 0, stream,
                     ws, none_p, out);
}